// Round 7
// baseline (969.016 us; speedup 1.0000x reference)
//
#include <hip/hip_runtime.h>

#define N_USERS   200000
#define N_ITEMS   100000
#define DIM       64
#define N_NODES   300000
#define N_EDGES   1200000
#define BIN_SHIFT 8
#define NBINS     1172            // ceil(300000/256)
#define CHUNK     4096
#define NCHUNKS   293             // ceil(1200000/4096)
#define BIN_CAP   2048            // mean edges/bin = 1024 -> huge margin
#define BGRID     2048            // 8 blocks/CU x 256 CU = exact capacity (pigeonhole => co-resident)
#define NCTR      32              // striped arrival counters

typedef unsigned long long u64;

// ---- bf16 helpers (manual RNE; no NaN inputs here) ------------------------
__device__ __forceinline__ unsigned short f2b(float f) {
    unsigned u = __float_as_uint(f);
    u += 0x7FFFu + ((u >> 16) & 1u);
    return (unsigned short)(u >> 16);
}
__device__ __forceinline__ float blo(unsigned w) { return __uint_as_float(w << 16); }
__device__ __forceinline__ float bhi(unsigned w) { return __uint_as_float(w & 0xFFFF0000u); }
__device__ __forceinline__ unsigned packbf(float lo, float hi) {
    return (unsigned)f2b(lo) | ((unsigned)f2b(hi) << 16);
}

// ---- L2-bypassing (coherence-point) accessors -----------------------------
// Agent-scope RELAXED atomics compile to sc-flagged ops performed at the
// shared L3: stores are immediately visible device-wide, loads always fresh.
// No wbl2/inv is ever emitted (that was R5/R6's 300 us barrier cost).
__device__ __forceinline__ void ast(int* p, int v) {
    __hip_atomic_store(p, v, __ATOMIC_RELAXED, __HIP_MEMORY_SCOPE_AGENT);
}
__device__ __forceinline__ void astf(float* p, float v) {
    __hip_atomic_store(p, v, __ATOMIC_RELAXED, __HIP_MEMORY_SCOPE_AGENT);
}
__device__ __forceinline__ void ast8(u64* p, u64 v) {
    __hip_atomic_store(p, v, __ATOMIC_RELAXED, __HIP_MEMORY_SCOPE_AGENT);
}
__device__ __forceinline__ int ald(const int* p) {
    return __hip_atomic_load(p, __ATOMIC_RELAXED, __HIP_MEMORY_SCOPE_AGENT);
}

// Fence-free grid barrier: relaxed striped arrival (32 lines -> no same-line
// RMW serialization), block-0 detector sums the stripes, relaxed epoch flag,
// s_sleep backoff. Correctness of data handoff comes from the sc1 stores
// above (data already at L3 when vmcnt drains inside __syncthreads), not
// from barrier fences.
__device__ __forceinline__ void gbar(int* ctr, int* flag, int phase) {
    __syncthreads();
    if (threadIdx.x == 0) {
        __hip_atomic_fetch_add(&ctr[blockIdx.x & (NCTR - 1)], 1,
                               __ATOMIC_RELAXED, __HIP_MEMORY_SCOPE_AGENT);
        if (blockIdx.x == 0) {
            const int target = BGRID * (phase + 1);
            for (;;) {
                int s = 0;
#pragma unroll
                for (int i = 0; i < NCTR; ++i) s += ald(&ctr[i]);
                if (s >= target) break;
                __builtin_amdgcn_s_sleep(8);
            }
            ast(flag, phase + 1);
        } else {
            while (ald(flag) <= phase) __builtin_amdgcn_s_sleep(64);
        }
    }
    __syncthreads();
}

// ---------------------------------------------------------------------------
// Pull layer (round-0 structure, grid-strided): 8 lanes/node, 16 B gathers,
// 4-way unroll. Non-FINAL writes g_out via 2x8B coherence-point stores
// (next phase plain-gathers them: first-touch -> fresh from L3).
template <bool FINAL>
__device__ __forceinline__ void pull_phase(
        const unsigned short* __restrict__ g_in,
        const int* __restrict__ row_ptr, const int* __restrict__ col_e,
        const float* __restrict__ dis, const float* __restrict__ invd,
        const float* __restrict__ ue, const float* __restrict__ ie,
        const unsigned short* __restrict__ gA,
        const unsigned short* __restrict__ gB,
        unsigned short* __restrict__ g_out,
        float* __restrict__ out) {
    int tid8 = threadIdx.x >> 3;
    int q    = threadIdx.x & 7;
    const uint4* gin4 = (const uint4*)g_in;   // row = 8 uint4
    for (int node = blockIdx.x * 32 + tid8; node < N_NODES; node += BGRID * 32) {
        int jb = row_ptr[node];
        int je = row_ptr[node + 1];
        float acc[8];
#pragma unroll
        for (int k = 0; k < 8; ++k) acc[k] = 0.f;
        auto accum = [&](uint4 u) {
            acc[0] += blo(u.x); acc[1] += bhi(u.x);
            acc[2] += blo(u.y); acc[3] += bhi(u.y);
            acc[4] += blo(u.z); acc[5] += bhi(u.z);
            acc[6] += blo(u.w); acc[7] += bhi(u.w);
        };
        int j = jb;
        for (; j + 3 < je; j += 4) {
            int c0 = col_e[j], c1 = col_e[j + 1], c2 = col_e[j + 2], c3 = col_e[j + 3];
            uint4 u0 = gin4[c0 * 8 + q];
            uint4 u1 = gin4[c1 * 8 + q];
            uint4 u2 = gin4[c2 * 8 + q];
            uint4 u3 = gin4[c3 * 8 + q];
            accum(u0); accum(u1); accum(u2); accum(u3);
        }
        for (; j < je; ++j) {
            uint4 u = gin4[col_e[j] * 8 + q];
            accum(u);
        }
        float dr = dis[node];
        if (!FINAL) {
            float s = dr * dr;
            unsigned w0 = packbf(s * acc[0], s * acc[1]);
            unsigned w1 = packbf(s * acc[2], s * acc[3]);
            unsigned w2 = packbf(s * acc[4], s * acc[5]);
            unsigned w3 = packbf(s * acc[6], s * acc[7]);
            u64* p = (u64*)(g_out + node * DIM) + 2 * q;
            ast8(p,     (u64)w0 | ((u64)w1 << 32));
            ast8(p + 1, (u64)w2 | ((u64)w3 << 32));
        } else {
            float iv = invd[node];
            const float* xs = (node < N_USERS) ? (ue + node * DIM)
                                               : (ie + (node - N_USERS) * DIM);
            float4 x0 = ((const float4*)xs)[2 * q];
            float4 x1 = ((const float4*)xs)[2 * q + 1];
            uint4 a = ((const uint4*)gA)[node * 8 + q];
            uint4 b = ((const uint4*)gB)[node * 8 + q];
            float4 o0, o1;
            o0.x = 0.25f * (x0.x + (blo(a.x) + blo(b.x)) * iv + dr * acc[0]);
            o0.y = 0.25f * (x0.y + (bhi(a.x) + bhi(b.x)) * iv + dr * acc[1]);
            o0.z = 0.25f * (x0.z + (blo(a.y) + blo(b.y)) * iv + dr * acc[2]);
            o0.w = 0.25f * (x0.w + (bhi(a.y) + bhi(b.y)) * iv + dr * acc[3]);
            o1.x = 0.25f * (x1.x + (blo(a.z) + blo(b.z)) * iv + dr * acc[4]);
            o1.y = 0.25f * (x1.y + (bhi(a.z) + bhi(b.z)) * iv + dr * acc[5]);
            o1.z = 0.25f * (x1.z + (blo(a.w) + blo(b.w)) * iv + dr * acc[6]);
            o1.w = 0.25f * (x1.w + (bhi(a.w) + bhi(b.w)) * iv + dr * acc[7]);
            ((float4*)out)[node * 16 + 2 * q]     = o0;
            ((float4*)out)[node * 16 + 2 * q + 1] = o1;
        }
    }
}

// ---------------------------------------------------------------------------
// ONE kernel: CSR build (hist -> scan -> place -> sort+conv) + 3 pull layers.
// 6 fence-free grid barriers; replaces 7 dispatches.
__global__ __launch_bounds__(256, 8) void fused_kernel(
        const int* __restrict__ row, const int* __restrict__ col,
        int* __restrict__ histG, int* __restrict__ binTot,
        int* __restrict__ ctr, int* __restrict__ flag,
        int* __restrict__ binStart,
        int* __restrict__ tmp, int* __restrict__ col_e,
        int* __restrict__ row_ptr, float* __restrict__ dis,
        float* __restrict__ invd,
        const float* __restrict__ ue, const float* __restrict__ ie,
        unsigned short* __restrict__ g0, unsigned short* __restrict__ g1,
        unsigned short* __restrict__ g2, float* __restrict__ out) {
    __shared__ int smem[2560];                 // 10.25 KB union of all phases
    int* h       = smem;                       // P0/P2: NBINS cursors
    int* hist    = smem;                       // P3
    int* lofs    = smem + 256;                 // P3
    int* colsOut = smem + 512;                 // P3: BIN_CAP ints

    // ---------------- P0: per-chunk histogram over bins -------------------
    int c = blockIdx.x;
    if (c < NCHUNKS) {
        for (int i = threadIdx.x; i < NBINS; i += 256) h[i] = 0;
        __syncthreads();
        const int4* row4 = (const int4*)row;
        int base4 = c * (CHUNK / 4);           // N_EDGES % 4 == 0
        int end4  = min(base4 + CHUNK / 4, N_EDGES / 4);
        int i0 = base4 + threadIdx.x;
        int i1 = i0 + 256, i2 = i0 + 512, i3 = i0 + 768;
        int4 r0, r1, r2, r3;
        bool v0 = i0 < end4, v1 = i1 < end4, v2 = i2 < end4, v3 = i3 < end4;
        if (v0) r0 = row4[i0];
        if (v1) r1 = row4[i1];
        if (v2) r2 = row4[i2];
        if (v3) r3 = row4[i3];
        if (v0) { atomicAdd(&h[r0.x >> BIN_SHIFT], 1); atomicAdd(&h[r0.y >> BIN_SHIFT], 1);
                  atomicAdd(&h[r0.z >> BIN_SHIFT], 1); atomicAdd(&h[r0.w >> BIN_SHIFT], 1); }
        if (v1) { atomicAdd(&h[r1.x >> BIN_SHIFT], 1); atomicAdd(&h[r1.y >> BIN_SHIFT], 1);
                  atomicAdd(&h[r1.z >> BIN_SHIFT], 1); atomicAdd(&h[r1.w >> BIN_SHIFT], 1); }
        if (v2) { atomicAdd(&h[r2.x >> BIN_SHIFT], 1); atomicAdd(&h[r2.y >> BIN_SHIFT], 1);
                  atomicAdd(&h[r2.z >> BIN_SHIFT], 1); atomicAdd(&h[r2.w >> BIN_SHIFT], 1); }
        if (v3) { atomicAdd(&h[r3.x >> BIN_SHIFT], 1); atomicAdd(&h[r3.y >> BIN_SHIFT], 1);
                  atomicAdd(&h[r3.z >> BIN_SHIFT], 1); atomicAdd(&h[r3.w >> BIN_SHIFT], 1); }
        __syncthreads();
        for (int i = threadIdx.x; i < NBINS; i += 256) {
            int v = h[i];
            ast(&histG[c * NBINS + i], v);     // -> L3 (P1/P2 read it cross-XCD)
            if (v) atomicAdd(&binTot[i], v);   // device-scope RMW: already at L3
        }
    }
    gbar(ctr, flag, 0);

    // ---------------- P1: bin prefix + chunk-scan rewrite (wave 0) --------
    if (threadIdx.x < 64) {
        int lane = threadIdx.x;
        for (int b = blockIdx.x; b < NBINS; b += BGRID) {
            int pre = 0;
            for (int i = lane; i < b; i += 64) pre += binTot[i];   // first plain touch: fresh
#pragma unroll
            for (int off = 1; off < 64; off <<= 1) pre += __shfl_xor(pre, off, 64);
            if (lane == 0) ast(&binStart[b], pre);
            if (b == 0 && lane == 0) ast(&binStart[NBINS], N_EDGES);
            int carry = pre;
            for (int base = 0; base < NCHUNKS; base += 64) {
                int idx = base + lane;
                int v = (idx < NCHUNKS) ? histG[idx * NBINS + b] : 0;  // first plain touch
                int incl = v;
                for (int off = 1; off < 64; off <<= 1) {
                    int t = __shfl_up(incl, off, 64);
                    if (lane >= off) incl += t;
                }
                if (idx < NCHUNKS) ast(&histG[idx * NBINS + b], carry + incl - v);
                carry += __shfl(incl, 63, 64);
            }
        }
    }
    gbar(ctr, flag, 1);

    // ---------------- P2: place packed (col<<8 | row&255) into tmp --------
    if (c < NCHUNKS) {
        for (int i = threadIdx.x; i < NBINS; i += 256)
            h[i] = ald(&histG[c * NBINS + i]); // P1 plain-reads cached stale copies -> must bypass
        __syncthreads();
        const int4* row4 = (const int4*)row;
        const int4* col4 = (const int4*)col;
        int base4 = c * (CHUNK / 4);
        int end4  = min(base4 + CHUNK / 4, N_EDGES / 4);
        int i0 = base4 + threadIdx.x;
        int i1 = i0 + 256, i2 = i0 + 512, i3 = i0 + 768;
        int4 r0, r1, r2, r3, c0, c1, c2, c3;
        bool v0 = i0 < end4, v1 = i1 < end4, v2 = i2 < end4, v3 = i3 < end4;
        if (v0) { r0 = row4[i0]; c0 = col4[i0]; }
        if (v1) { r1 = row4[i1]; c1 = col4[i1]; }
        if (v2) { r2 = row4[i2]; c2 = col4[i2]; }
        if (v3) { r3 = row4[i3]; c3 = col4[i3]; }
        auto put = [&](int r, int cc) {
            int pos = atomicAdd(&h[r >> BIN_SHIFT], 1);
            ast(&tmp[pos], (cc << BIN_SHIFT) | (r & 255));
        };
        if (v0) { put(r0.x, c0.x); put(r0.y, c0.y); put(r0.z, c0.z); put(r0.w, c0.w); }
        if (v1) { put(r1.x, c1.x); put(r1.y, c1.y); put(r1.z, c1.z); put(r1.w, c1.w); }
        if (v2) { put(r2.x, c2.x); put(r2.y, c2.y); put(r2.z, c2.z); put(r2.w, c2.w); }
        if (v3) { put(r3.x, c3.x); put(r3.y, c3.y); put(r3.z, c3.z); put(r3.w, c3.w); }
    }
    gbar(ctr, flag, 2);

    // ---------------- P3: per-bin counting sort + row_ptr/dis + conv ------
    int b = blockIdx.x;
    if (b < NBINS) {
        int jb = binStart[b], je = binStart[b + 1];  // first plain touch: fresh
        int n  = je - jb;
        hist[threadIdx.x] = 0;
        __syncthreads();
        int ed[8], rk[8];
        int cnt8 = 0;
        for (int i = threadIdx.x; i < n && cnt8 < 8; i += 256) {
            int rc = tmp[jb + i];                    // first plain touch: fresh
            ed[cnt8] = rc;
            rk[cnt8] = atomicAdd(&hist[rc & 255], 1);
            cnt8++;
        }
        __syncthreads();
        int deg = hist[threadIdx.x];
        lofs[threadIdx.x] = deg;
        __syncthreads();
        for (int off = 1; off < 256; off <<= 1) {
            int t = (threadIdx.x >= off) ? lofs[threadIdx.x - off] : 0;
            __syncthreads();
            lofs[threadIdx.x] += t;
            __syncthreads();
        }
        int myEx = lofs[threadIdx.x] - deg;
        int node = (b << BIN_SHIFT) + threadIdx.x;
        if (node < N_NODES) {
            ast(&row_ptr[node], jb + myEx);
            float fd = (float)deg;
            astf(&dis[node],  (deg > 0) ? rsqrtf(fd) : 0.0f);
            astf(&invd[node], (deg > 0) ? sqrtf(fd)  : 0.0f);
        }
        if (b == 0 && threadIdx.x == 0) ast(&row_ptr[N_NODES], N_EDGES);
        lofs[threadIdx.x] = myEx;
        __syncthreads();
        for (int k = 0; k < cnt8; ++k)
            colsOut[lofs[ed[k] & 255] + rk[k]] = ((unsigned)ed[k]) >> BIN_SHIFT;
        __syncthreads();
        for (int i = threadIdx.x; i < n; i += 256)
            ast(&col_e[jb + i], colsOut[i]);

        // fused conv: g0 rows for nodes [b*256, b*256+256), 8 lanes/node
        int q = threadIdx.x & 7;
        for (int pass = 0; pass < 8; ++pass) {
            int nl = pass * 32 + (threadIdx.x >> 3);
            int nd = (b << BIN_SHIFT) + nl;
            if (nd >= N_NODES) break;
            int dg = hist[nl];
            float w = (dg > 0) ? rsqrtf((float)dg) : 0.0f;
            const float* src = (nd < N_USERS) ? (ue + nd * DIM)
                                              : (ie + (nd - N_USERS) * DIM);
            float4 x0 = ((const float4*)src)[2 * q];
            float4 x1 = ((const float4*)src)[2 * q + 1];
            unsigned w0 = packbf(w * x0.x, w * x0.y);
            unsigned w1 = packbf(w * x0.z, w * x0.w);
            unsigned w2 = packbf(w * x1.x, w * x1.y);
            unsigned w3 = packbf(w * x1.z, w * x1.w);
            u64* p = (u64*)(g0 + nd * DIM) + 2 * q;
            ast8(p,     (u64)w0 | ((u64)w1 << 32));
            ast8(p + 1, (u64)w2 | ((u64)w3 << 32));
        }
    }
    gbar(ctr, flag, 3);

    // ---------------- P4..P6: three pull layers ---------------------------
    pull_phase<false>(g0, row_ptr, col_e, dis, invd, nullptr, nullptr,
                      nullptr, nullptr, g1, nullptr);
    gbar(ctr, flag, 4);
    pull_phase<false>(g1, row_ptr, col_e, dis, invd, nullptr, nullptr,
                      nullptr, nullptr, g2, nullptr);
    gbar(ctr, flag, 5);
    pull_phase<true >(g2, row_ptr, col_e, dis, invd, ue, ie,
                      g1, g2, nullptr, out);
}

extern "C" void kernel_launch(void* const* d_in, const int* in_sizes, int n_in,
                              void* d_out, int out_size, void* d_ws, size_t ws_size,
                              hipStream_t stream) {
    const float* ue  = (const float*)d_in[0];
    const float* ie  = (const float*)d_in[1];
    const int*   ei  = (const int*)d_in[2];
    const int*   row = ei;
    const int*   col = ei + N_EDGES;
    float*       out = (float*)d_out;

    // workspace layout (~135 MB)
    size_t gElems = (size_t)N_NODES * DIM;                 // 19.2 M
    unsigned short* g0 = (unsigned short*)d_ws;            // 38.4 MB
    unsigned short* g1 = g0 + gElems;                      // 38.4 MB
    unsigned short* g2 = g1 + gElems;                      // 38.4 MB
    int*   tmp      = (int*)(g2 + gElems);                 // 4.8 MB (packed)
    int*   col_e    = tmp + N_EDGES;                       // 4.8 MB
    int*   row_ptr  = col_e + N_EDGES;                     // 1.2 MB
    float* dis      = (float*)(row_ptr + N_NODES + 1);
    float* invd     = dis + N_NODES;
    int*   histG    = (int*)(invd + N_NODES);              // 293*1172*4 = 1.37 MB
    int*   binTot   = histG + NCHUNKS * NBINS;             // NBINS
    int*   ctr      = binTot + NBINS;                      // NCTR striped arrivals
    int*   flag     = ctr + NCTR;                          // epoch flag (+pad)
    int*   binStart = flag + 8;                            // NBINS+1

    // zero binTot + ctr + flag in one memset (stream-ordered before kernel)
    hipMemsetAsync(binTot, 0, (size_t)(NBINS + NCTR + 8) * sizeof(int), stream);
    fused_kernel<<<BGRID, 256, 0, stream>>>(row, col, histG, binTot, ctr, flag,
                                            binStart, tmp, col_e, row_ptr,
                                            dis, invd, ue, ie, g0, g1, g2, out);
}

// Round 8
// 285.568 us; speedup vs baseline: 3.3933x; 3.3933x over previous
//
#include <hip/hip_runtime.h>

#define N_USERS   200000
#define N_ITEMS   100000
#define DIM       64
#define N_NODES   300000
#define N_EDGES   1200000
#define BIN_SHIFT 8
#define NBINS     1172            // ceil(300000/256)
#define CHUNK     4096
#define NCHUNKS   293             // ceil(1200000/4096)
#define BIN_CAP   2048            // fixed region/bin; mean fill 1024, +32 sigma margin

// ---- bf16 helpers (manual RNE; no NaN inputs here) ------------------------
__device__ __forceinline__ unsigned short f2b(float f) {
    unsigned u = __float_as_uint(f);
    u += 0x7FFFu + ((u >> 16) & 1u);
    return (unsigned short)(u >> 16);
}
__device__ __forceinline__ float blo(unsigned w) { return __uint_as_float(w << 16); }
__device__ __forceinline__ float bhi(unsigned w) { return __uint_as_float(w & 0xFFFF0000u); }
__device__ __forceinline__ unsigned packbf(float lo, float hi) {
    return (unsigned)f2b(lo) | ((unsigned)f2b(hi) << 16);
}

// ---------------------------------------------------------------------------
// Fused histogram+reserve+place: per 4096-edge chunk. LDS histogram, ONE
// global atomicAdd per touched bin reserves a range in the bin's fixed
// BIN_CAP region (no global prefix scan anywhere), then places packed
// (col<<8 | row&255). Replaces histA + rewrite + placeA (3 kernels -> 1).
__global__ __launch_bounds__(256) void buildA_kernel(const int* __restrict__ row,
                                                     const int* __restrict__ col,
                                                     int* __restrict__ binCnt,
                                                     int* __restrict__ tmp) {
    __shared__ int h[NBINS];
    for (int i = threadIdx.x; i < NBINS; i += 256) h[i] = 0;
    __syncthreads();
    const int4* row4 = (const int4*)row;
    const int4* col4 = (const int4*)col;
    int base4 = blockIdx.x * (CHUNK / 4);                 // N_EDGES % 4 == 0
    int end4  = min(base4 + CHUNK / 4, N_EDGES / 4);
    int i0 = base4 + threadIdx.x;
    int i1 = i0 + 256, i2 = i0 + 512, i3 = i0 + 768;
    int4 r0, r1, r2, r3, c0, c1, c2, c3;
    bool v0 = i0 < end4, v1 = i1 < end4, v2 = i2 < end4, v3 = i3 < end4;
    if (v0) { r0 = row4[i0]; c0 = col4[i0]; }
    if (v1) { r1 = row4[i1]; c1 = col4[i1]; }
    if (v2) { r2 = row4[i2]; c2 = col4[i2]; }
    if (v3) { r3 = row4[i3]; c3 = col4[i3]; }
    if (v0) { atomicAdd(&h[r0.x >> BIN_SHIFT], 1); atomicAdd(&h[r0.y >> BIN_SHIFT], 1);
              atomicAdd(&h[r0.z >> BIN_SHIFT], 1); atomicAdd(&h[r0.w >> BIN_SHIFT], 1); }
    if (v1) { atomicAdd(&h[r1.x >> BIN_SHIFT], 1); atomicAdd(&h[r1.y >> BIN_SHIFT], 1);
              atomicAdd(&h[r1.z >> BIN_SHIFT], 1); atomicAdd(&h[r1.w >> BIN_SHIFT], 1); }
    if (v2) { atomicAdd(&h[r2.x >> BIN_SHIFT], 1); atomicAdd(&h[r2.y >> BIN_SHIFT], 1);
              atomicAdd(&h[r2.z >> BIN_SHIFT], 1); atomicAdd(&h[r2.w >> BIN_SHIFT], 1); }
    if (v3) { atomicAdd(&h[r3.x >> BIN_SHIFT], 1); atomicAdd(&h[r3.y >> BIN_SHIFT], 1);
              atomicAdd(&h[r3.z >> BIN_SHIFT], 1); atomicAdd(&h[r3.w >> BIN_SHIFT], 1); }
    __syncthreads();
    // reserve: count -> within-bin base (in place)
    for (int i = threadIdx.x; i < NBINS; i += 256) {
        int v = h[i];
        if (v) h[i] = atomicAdd(&binCnt[i], v);
    }
    __syncthreads();
    auto put = [&](int r, int cc) {
        int bin = r >> BIN_SHIFT;
        int pos = atomicAdd(&h[bin], 1);
        tmp[bin * BIN_CAP + pos] = (cc << BIN_SHIFT) | (r & 255);
    };
    if (v0) { put(r0.x, c0.x); put(r0.y, c0.y); put(r0.z, c0.z); put(r0.w, c0.w); }
    if (v1) { put(r1.x, c1.x); put(r1.y, c1.y); put(r1.z, c1.z); put(r1.w, c1.w); }
    if (v2) { put(r2.x, c2.x); put(r2.y, c2.y); put(r2.z, c2.z); put(r2.w, c2.w); }
    if (v3) { put(r3.x, c3.x); put(r3.y, c3.y); put(r3.z, c3.z); put(r3.w, c3.w); }
}

// ---------------------------------------------------------------------------
// Per-bin LDS counting sort by (row&255); emits col_e (bin-region layout),
// 16 B per-node records {jb, deg, dis_bits, invd_bits}, and FUSED conv
// (g0 = x*dis bf16) for the bin's 256 nodes.
__global__ __launch_bounds__(256) void binsortB_kernel(const int* __restrict__ tmp,
                                                       const int* __restrict__ binCnt,
                                                       int* __restrict__ col_e,
                                                       uint4* __restrict__ rec,
                                                       const float* __restrict__ ue,
                                                       const float* __restrict__ ie,
                                                       unsigned short* __restrict__ g0) {
    __shared__ int hist[256];
    __shared__ int lofs[256];
    __shared__ int colsOut[BIN_CAP];
    int b  = blockIdx.x;
    int jb = b * BIN_CAP;
    int n  = binCnt[b];
    hist[threadIdx.x] = 0;
    __syncthreads();
    int ed[8], rk[8];
    int cnt = 0;
    for (int i = threadIdx.x; i < n && cnt < 8; i += 256) {
        int rc = tmp[jb + i];
        ed[cnt] = rc;
        rk[cnt] = atomicAdd(&hist[rc & 255], 1);
        cnt++;
    }
    __syncthreads();
    int deg = hist[threadIdx.x];
    lofs[threadIdx.x] = deg;
    __syncthreads();
    for (int off = 1; off < 256; off <<= 1) {
        int t = (threadIdx.x >= off) ? lofs[threadIdx.x - off] : 0;
        __syncthreads();
        lofs[threadIdx.x] += t;
        __syncthreads();
    }
    int myEx = lofs[threadIdx.x] - deg;
    int node = (b << BIN_SHIFT) + threadIdx.x;
    if (node < N_NODES) {
        float fd = (float)deg;
        float dr = (deg > 0) ? rsqrtf(fd) : 0.0f;
        float iv = (deg > 0) ? sqrtf(fd)  : 0.0f;
        uint4 r;
        r.x = (unsigned)(jb + myEx);
        r.y = (unsigned)deg;
        r.z = __float_as_uint(dr);
        r.w = __float_as_uint(iv);
        rec[node] = r;
    }
    lofs[threadIdx.x] = myEx;
    __syncthreads();
    for (int k = 0; k < cnt; ++k)
        colsOut[lofs[ed[k] & 255] + rk[k]] = ((unsigned)ed[k]) >> BIN_SHIFT;
    __syncthreads();
    for (int i = threadIdx.x; i < n; i += 256)
        col_e[jb + i] = colsOut[i];

    // ---- fused conv: g0 rows for nodes [b*256, b*256+256), 8 lanes/node ----
    int q = threadIdx.x & 7;
    for (int pass = 0; pass < 8; ++pass) {
        int nl = pass * 32 + (threadIdx.x >> 3);
        int nd = (b << BIN_SHIFT) + nl;
        if (nd >= N_NODES) break;
        int dg = hist[nl];
        float w = (dg > 0) ? rsqrtf((float)dg) : 0.0f;
        const float* src = (nd < N_USERS) ? (ue + nd * DIM)
                                          : (ie + (nd - N_USERS) * DIM);
        float4 x0 = ((const float4*)src)[2 * q];
        float4 x1 = ((const float4*)src)[2 * q + 1];
        uint4 o;
        o.x = packbf(w * x0.x, w * x0.y);
        o.y = packbf(w * x0.z, w * x0.w);
        o.z = packbf(w * x1.x, w * x1.y);
        o.w = packbf(w * x1.z, w * x1.w);
        ((uint4*)(g0 + nd * DIM))[q] = o;
    }
}

// ---------------------------------------------------------------------------
// Atomic-free bf16 pull (round-0 inner loop -- best measured: 60.3 us):
// 8 lanes/node, 16 B gathers, 4-way edge unroll. ONE broadcast 16 B record
// load {jb, deg, dis, invd} replaces row_ptr[n] + row_ptr[n+1] + dis[n].
// g_{l+1}[r] = dis_r^2 * sum g_l[c].
// FINAL: out = 0.25*(x + (g1+g2)*sqrt(deg) + dis*sum g2[c])
template <bool FINAL>
__global__ __launch_bounds__(256) void pull_kernel(
        const unsigned short* __restrict__ g_in,
        const uint4* __restrict__ rec,
        const int* __restrict__ col_e,
        const float* __restrict__ ue, const float* __restrict__ ie,
        const unsigned short* __restrict__ gA,
        const unsigned short* __restrict__ gB,
        unsigned short* __restrict__ g_out,
        float* __restrict__ out) {
    int gid  = blockIdx.x * blockDim.x + threadIdx.x;
    int node = gid >> 3;
    int q    = gid & 7;
    if (node >= N_NODES) return;
    uint4 r = rec[node];
    int jb = (int)r.x;
    int je = jb + (int)r.y;
    const uint4* gin4 = (const uint4*)g_in;   // row = 8 uint4

    float acc[8];
#pragma unroll
    for (int k = 0; k < 8; ++k) acc[k] = 0.f;

    auto accum = [&](uint4 u) {
        acc[0] += blo(u.x); acc[1] += bhi(u.x);
        acc[2] += blo(u.y); acc[3] += bhi(u.y);
        acc[4] += blo(u.z); acc[5] += bhi(u.z);
        acc[6] += blo(u.w); acc[7] += bhi(u.w);
    };

    int j = jb;
    for (; j + 3 < je; j += 4) {
        int c0 = col_e[j], c1 = col_e[j + 1], c2 = col_e[j + 2], c3 = col_e[j + 3];
        uint4 u0 = gin4[c0 * 8 + q];
        uint4 u1 = gin4[c1 * 8 + q];
        uint4 u2 = gin4[c2 * 8 + q];
        uint4 u3 = gin4[c3 * 8 + q];
        accum(u0); accum(u1); accum(u2); accum(u3);
    }
    for (; j < je; ++j) {
        uint4 u = gin4[col_e[j] * 8 + q];
        accum(u);
    }

    float dr = __uint_as_float(r.z);
    if (!FINAL) {
        float s = dr * dr;
        uint4 o;
        o.x = packbf(s * acc[0], s * acc[1]);
        o.y = packbf(s * acc[2], s * acc[3]);
        o.z = packbf(s * acc[4], s * acc[5]);
        o.w = packbf(s * acc[6], s * acc[7]);
        ((uint4*)(g_out + node * DIM))[q] = o;
    } else {
        float iv = __uint_as_float(r.w);
        const float* xs = (node < N_USERS) ? (ue + node * DIM)
                                           : (ie + (node - N_USERS) * DIM);
        float4 x0 = ((const float4*)xs)[2 * q];
        float4 x1 = ((const float4*)xs)[2 * q + 1];
        uint4 a = ((const uint4*)gA)[node * 8 + q];
        uint4 b = ((const uint4*)gB)[node * 8 + q];
        float4 o0, o1;
        o0.x = 0.25f * (x0.x + (blo(a.x) + blo(b.x)) * iv + dr * acc[0]);
        o0.y = 0.25f * (x0.y + (bhi(a.x) + bhi(b.x)) * iv + dr * acc[1]);
        o0.z = 0.25f * (x0.z + (blo(a.y) + blo(b.y)) * iv + dr * acc[2]);
        o0.w = 0.25f * (x0.w + (bhi(a.y) + bhi(b.y)) * iv + dr * acc[3]);
        o1.x = 0.25f * (x1.x + (blo(a.z) + blo(b.z)) * iv + dr * acc[4]);
        o1.y = 0.25f * (x1.y + (bhi(a.z) + bhi(b.z)) * iv + dr * acc[5]);
        o1.z = 0.25f * (x1.z + (blo(a.w) + blo(b.w)) * iv + dr * acc[6]);
        o1.w = 0.25f * (x1.w + (bhi(a.w) + bhi(b.w)) * iv + dr * acc[7]);
        ((float4*)out)[node * 16 + 2 * q]     = o0;
        ((float4*)out)[node * 16 + 2 * q + 1] = o1;
    }
}

extern "C" void kernel_launch(void* const* d_in, const int* in_sizes, int n_in,
                              void* d_out, int out_size, void* d_ws, size_t ws_size,
                              hipStream_t stream) {
    const float* ue  = (const float*)d_in[0];
    const float* ie  = (const float*)d_in[1];
    const int*   ei  = (const int*)d_in[2];
    const int*   row = ei;
    const int*   col = ei + N_EDGES;
    float*       out = (float*)d_out;

    // workspace layout (~140 MB)
    size_t gElems = (size_t)N_NODES * DIM;                 // 19.2 M
    unsigned short* g0 = (unsigned short*)d_ws;            // 38.4 MB
    unsigned short* g1 = g0 + gElems;                      // 38.4 MB
    unsigned short* g2 = g1 + gElems;                      // 38.4 MB
    int*   tmp    = (int*)(g2 + gElems);                   // NBINS*BIN_CAP*4 = 9.6 MB
    int*   col_e  = tmp + NBINS * BIN_CAP;                 // 9.6 MB (bin regions)
    uint4* rec    = (uint4*)(col_e + NBINS * BIN_CAP);     // 4.8 MB
    int*   binCnt = (int*)(rec + N_NODES);                 // 4.7 KB

    const int B  = 256;
    const int GP = (N_NODES * 8 + B - 1) / B;

    // ---- CSR-lite build: memset + 2 kernels (was 5 dispatches) ----
    hipMemsetAsync(binCnt, 0, (size_t)NBINS * sizeof(int), stream);
    buildA_kernel  <<<NCHUNKS, B, 0, stream>>>(row, col, binCnt, tmp);
    binsortB_kernel<<<NBINS, B, 0, stream>>>(tmp, binCnt, col_e, rec, ue, ie, g0);

    // ---- 3 bf16 pull layers; acc + scale fused into the last epilogue ----
    pull_kernel<false><<<GP, B, 0, stream>>>(g0, rec, col_e, nullptr, nullptr,
                                             nullptr, nullptr, g1, nullptr);
    pull_kernel<false><<<GP, B, 0, stream>>>(g1, rec, col_e, nullptr, nullptr,
                                             nullptr, nullptr, g2, nullptr);
    pull_kernel<true ><<<GP, B, 0, stream>>>(g2, rec, col_e, ue, ie,
                                             g1, g2, nullptr, out);
}